// Round 1
// baseline (565.185 us; speedup 1.0000x reference)
//
#include <hip/hip_runtime.h>

#define BS   8
#define CH   256    // C
#define LSEQ 4096   // H*W
#define DIN  256    // INNER

typedef __bf16 bf16x8 __attribute__((ext_vector_type(8)));
typedef __bf16 bf16x4 __attribute__((ext_vector_type(4)));
typedef float  f32x4  __attribute__((ext_vector_type(4)));

// ---------------------------------------------------------------------------
// Kernel 1: QKV projection.
// Computes Y[l][i] = sum_c X[c][l] * W[i][c] + bias[i]  (per batch, per W).
// MFMA 16x16x32 bf16: A = Xt tile (m=l, k=c), B = W tile (k=c, n=i).
// which==0 -> Q stored [l][i]; which==1 -> K stored [l][i]; which==2 -> VT stored [i][l].
// ---------------------------------------------------------------------------
__global__ __launch_bounds__(256) void qkv_proj_kernel(
    const float* __restrict__ x,
    const float* __restrict__ Wq, const float* __restrict__ bq,
    const float* __restrict__ Wk, const float* __restrict__ bk,
    const float* __restrict__ Wv, const float* __restrict__ bv,
    __bf16* __restrict__ Q, __bf16* __restrict__ K, __bf16* __restrict__ VT)
{
    const int b     = blockIdx.z;
    const int which = blockIdx.y;
    const int l0    = blockIdx.x * 64;

    const float* W    = (which == 0) ? Wq : (which == 1) ? Wk : Wv;
    const float* bias = (which == 0) ? bq : (which == 1) ? bk : bv;
    const float* X    = x + (size_t)b * CH * LSEQ;

    // padded rows (40 elems = 80 B) -> fragment reads land on 8 banks (2-way, free)
    __shared__ __align__(16) __bf16 sXt[64][40];   // [l][c]
    __shared__ __align__(16) __bf16 sW[256][40];   // [i][c]

    const int tid  = threadIdx.x;
    const int wv   = tid >> 6;
    const int lane = tid & 63;
    const int g    = lane >> 4;
    const int n16  = lane & 15;

    f32x4 acc[4][4];
    #pragma unroll
    for (int i = 0; i < 4; ++i)
        #pragma unroll
        for (int j = 0; j < 4; ++j)
            acc[i][j] = f32x4{0.f, 0.f, 0.f, 0.f};

    for (int kk = 0; kk < 8; ++kk) {
        const int c0 = kk * 32;
        __syncthreads();
        // stage W k-slice [256 i][32 c], f32 -> bf16
        #pragma unroll
        for (int p = 0; p < 8; ++p) {
            const int i  = p * 32 + (tid >> 3);
            const int c4 = (tid & 7) * 4;
            const float4 v = *(const float4*)(W + (size_t)i * CH + c0 + c4);
            bf16x4 pk = { (__bf16)v.x, (__bf16)v.y, (__bf16)v.z, (__bf16)v.w };
            *(bf16x4*)&sW[i][c4] = pk;
        }
        // stage X k-slice transposed: sXt[l][c] = X[c][l]
        #pragma unroll
        for (int p = 0; p < 2; ++p) {
            const int c  = p * 16 + (tid >> 4);
            const int l4 = (tid & 15) * 4;
            const float4 v = *(const float4*)(X + (size_t)(c0 + c) * LSEQ + l0 + l4);
            sXt[l4 + 0][c] = (__bf16)v.x;
            sXt[l4 + 1][c] = (__bf16)v.y;
            sXt[l4 + 2][c] = (__bf16)v.z;
            sXt[l4 + 3][c] = (__bf16)v.w;
        }
        __syncthreads();

        bf16x8 af[4], bfr[4];
        #pragma unroll
        for (int mr = 0; mr < 4; ++mr)
            af[mr] = *(const bf16x8*)&sXt[mr * 16 + n16][g * 8];
        #pragma unroll
        for (int nc = 0; nc < 4; ++nc)
            bfr[nc] = *(const bf16x8*)&sW[wv * 64 + nc * 16 + n16][g * 8];
        #pragma unroll
        for (int mr = 0; mr < 4; ++mr)
            #pragma unroll
            for (int nc = 0; nc < 4; ++nc)
                acc[mr][nc] = __builtin_amdgcn_mfma_f32_16x16x32_bf16(
                    af[mr], bfr[nc], acc[mr][nc], 0, 0, 0);
    }

    // D fragment: row m = mr*16 + g*4 + r (l), col n = nc*16 + n16 (i)
    if (which < 2) {
        __bf16* out = ((which == 0) ? Q : K) + (size_t)b * LSEQ * DIN;
        #pragma unroll
        for (int nc = 0; nc < 4; ++nc) {
            const int icol = wv * 64 + nc * 16 + n16;
            const float bb = bias[icol];
            #pragma unroll
            for (int mr = 0; mr < 4; ++mr) {
                const int lrow = l0 + mr * 16 + g * 4;
                #pragma unroll
                for (int r = 0; r < 4; ++r)
                    out[(size_t)(lrow + r) * DIN + icol] = (__bf16)(acc[mr][nc][r] + bb);
            }
        }
    } else {
        __bf16* out = VT + (size_t)b * DIN * LSEQ;   // [i][l]
        #pragma unroll
        for (int nc = 0; nc < 4; ++nc) {
            const int icol = wv * 64 + nc * 16 + n16;
            const float bb = bias[icol];
            #pragma unroll
            for (int mr = 0; mr < 4; ++mr) {
                const int lrow = l0 + mr * 16 + g * 4;
                bf16x4 pk;
                #pragma unroll
                for (int r = 0; r < 4; ++r)
                    pk[r] = (__bf16)(acc[mr][nc][r] + bb);
                *(bf16x4*)&out[(size_t)icol * LSEQ + lrow] = pk;  // 4 consecutive l -> 8B store
            }
        }
    }
}

// ---------------------------------------------------------------------------
// Kernel 2: flash attention. Block = 4 waves, 64 q-rows (16/wave), KV tile 64.
// Q[l][d], K[l][d] feed QK^T directly; VT[d][l] feeds PV B-fragments directly.
// Online softmax; folded scale: p = exp2((s_raw - m_raw) * log2(e)/16).
// Grid (b, qtile): all 64 blocks of a batch land on one XCD -> K/V L2-resident.
// ---------------------------------------------------------------------------
__global__ __launch_bounds__(256) void attn_kernel(
    const __bf16* __restrict__ Q, const __bf16* __restrict__ K,
    const __bf16* __restrict__ VT, __bf16* __restrict__ O)
{
    const int b   = blockIdx.x;
    const int q0  = blockIdx.y * 64;
    const int tid = threadIdx.x;
    const int wv  = tid >> 6, lane = tid & 63, g = lane >> 4, n16 = lane & 15;

    __shared__ __align__(16) __bf16 sK[64][264];   // [kj][d], pad 264
    __shared__ __align__(16) __bf16 sVT[256][72];  // [d][kj], pad 72
    __shared__ __align__(16) __bf16 sP[64][72];    // [qi][kj], per-wave-private rows

    // Q fragments: A[m=qi][k=d], lane row = n16, k = g*8+j; 8 k-slices of 32
    bf16x8 qf[8];
    {
        const __bf16* Qrow = Q + ((size_t)b * LSEQ + q0 + wv * 16 + n16) * DIN;
        #pragma unroll
        for (int ks = 0; ks < 8; ++ks)
            qf[ks] = *(const bf16x8*)(Qrow + ks * 32 + g * 8);
    }

    float m_i[4], l_i[4];
    #pragma unroll
    for (int r = 0; r < 4; ++r) { m_i[r] = -__builtin_inff(); l_i[r] = 0.f; }
    f32x4 accO[16];
    #pragma unroll
    for (int ds = 0; ds < 16; ++ds) accO[ds] = f32x4{0.f, 0.f, 0.f, 0.f};

    const __bf16* Kb = K  + (size_t)b * LSEQ * DIN;
    const __bf16* Vb = VT + (size_t)b * DIN * LSEQ;
    const float CEXP = 1.4426950408889634f / 16.0f;  // log2(e) / scale(=16)

    for (int kt = 0; kt < 64; ++kt) {
        const int k0 = kt * 64;
        __syncthreads();   // all waves done reading previous sK/sVT
        // stage K tile [64][256] bf16 (16B per lane per pass)
        #pragma unroll
        for (int p = 0; p < 8; ++p) {
            const int kj = p * 8 + (tid >> 5);
            const int sg = tid & 31;
            *(uint4*)&sK[kj][sg * 8] = *(const uint4*)(Kb + (size_t)(k0 + kj) * DIN + sg * 8);
        }
        // stage VT tile [256][64]
        #pragma unroll
        for (int p = 0; p < 8; ++p) {
            const int d  = p * 32 + (tid >> 3);
            const int sg = tid & 7;
            *(uint4*)&sVT[d][sg * 8] = *(const uint4*)(Vb + (size_t)d * LSEQ + k0 + sg * 8);
        }
        __syncthreads();

        // S = Q K^T : D[qi][kj]; B[k=d][n=kj]: lane reads sK[kj=nc*16+n16][d=ks*32+g*8..]
        f32x4 sacc[4];
        #pragma unroll
        for (int nc = 0; nc < 4; ++nc) sacc[nc] = f32x4{0.f, 0.f, 0.f, 0.f};
        #pragma unroll
        for (int nc = 0; nc < 4; ++nc) {
            #pragma unroll
            for (int ks = 0; ks < 8; ++ks) {
                const bf16x8 kf = *(const bf16x8*)&sK[nc * 16 + n16][ks * 32 + g * 8];
                sacc[nc] = __builtin_amdgcn_mfma_f32_16x16x32_bf16(qf[ks], kf, sacc[nc], 0, 0, 0);
            }
        }

        // online softmax; lane holds rows qi_local = g*4 + r, cols nc*16 + n16
        float scl[4], pr[4][4];
        #pragma unroll
        for (int r = 0; r < 4; ++r) {
            float rmax = fmaxf(fmaxf(sacc[0][r], sacc[1][r]), fmaxf(sacc[2][r], sacc[3][r]));
            rmax = fmaxf(rmax, __shfl_xor(rmax, 1));
            rmax = fmaxf(rmax, __shfl_xor(rmax, 2));
            rmax = fmaxf(rmax, __shfl_xor(rmax, 4));
            rmax = fmaxf(rmax, __shfl_xor(rmax, 8));
            const float mnew = fmaxf(m_i[r], rmax);
            scl[r] = exp2f((m_i[r] - mnew) * CEXP);
            float rsum = 0.f;
            #pragma unroll
            for (int nc = 0; nc < 4; ++nc) {
                const float pv = exp2f((sacc[nc][r] - mnew) * CEXP);
                pr[r][nc] = pv;
                rsum += pv;
            }
            rsum += __shfl_xor(rsum, 1);
            rsum += __shfl_xor(rsum, 2);
            rsum += __shfl_xor(rsum, 4);
            rsum += __shfl_xor(rsum, 8);
            l_i[r] = l_i[r] * scl[r] + rsum;
            m_i[r] = mnew;
        }
        // rescale O accumulator
        #pragma unroll
        for (int ds = 0; ds < 16; ++ds)
            #pragma unroll
            for (int r = 0; r < 4; ++r)
                accO[ds][r] *= scl[r];

        // P -> LDS (wave-private rows; DS ops in-order per wave, no barrier needed)
        #pragma unroll
        for (int r = 0; r < 4; ++r)
            #pragma unroll
            for (int nc = 0; nc < 4; ++nc)
                sP[wv * 16 + g * 4 + r][nc * 16 + n16] = (__bf16)pr[r][nc];

        // PV: A = P (rows qi = n16), B = V (sVT[d][kj], 8 consecutive kj per lane)
        #pragma unroll
        for (int ks2 = 0; ks2 < 2; ++ks2) {
            const bf16x8 af = *(const bf16x8*)&sP[wv * 16 + n16][ks2 * 32 + g * 8];
            #pragma unroll
            for (int ds = 0; ds < 16; ++ds) {
                const bf16x8 vf = *(const bf16x8*)&sVT[ds * 16 + n16][ks2 * 32 + g * 8];
                accO[ds] = __builtin_amdgcn_mfma_f32_16x16x32_bf16(af, vf, accO[ds], 0, 0, 0);
            }
        }
    }

    // epilogue: O[l][d] = accO / l_i, bf16
    float inv[4];
    #pragma unroll
    for (int r = 0; r < 4; ++r) inv[r] = 1.f / l_i[r];
    __bf16* Ob = O + ((size_t)b * LSEQ + q0 + wv * 16) * DIN;
    #pragma unroll
    for (int ds = 0; ds < 16; ++ds)
        #pragma unroll
        for (int r = 0; r < 4; ++r)
            Ob[(size_t)(g * 4 + r) * DIN + ds * 16 + n16] = (__bf16)(accO[ds][r] * inv[r]);
}

// ---------------------------------------------------------------------------
// Kernel 3: output projection. out[b][c][l] = sum_i Wo[c][i]*O[b][l][i] + bo[c].
// A = Wo (m=c, k=i), B = O (k=i, n=l). f32 output in (B, C, L) layout.
// ---------------------------------------------------------------------------
__global__ __launch_bounds__(256) void out_proj_kernel(
    const float* __restrict__ Wo, const float* __restrict__ bo,
    const __bf16* __restrict__ O, float* __restrict__ out)
{
    const int b   = blockIdx.z;
    const int c0  = blockIdx.y * 64;
    const int l0  = blockIdx.x * 256;
    const int tid = threadIdx.x;
    const int wv  = tid >> 6, lane = tid & 63, g = lane >> 4, n16 = lane & 15;

    __shared__ __align__(16) __bf16 sWo[64][40];   // [c][i]
    __shared__ __align__(16) __bf16 sO[256][40];   // [l][i]

    const __bf16* Ob = O + (size_t)b * LSEQ * DIN;

    f32x4 acc[4][4];
    #pragma unroll
    for (int i = 0; i < 4; ++i)
        #pragma unroll
        for (int j = 0; j < 4; ++j)
            acc[i][j] = f32x4{0.f, 0.f, 0.f, 0.f};

    for (int kk = 0; kk < 8; ++kk) {
        const int i0 = kk * 32;
        __syncthreads();
        #pragma unroll
        for (int p = 0; p < 2; ++p) {
            const int c  = p * 32 + (tid >> 3);
            const int i4 = (tid & 7) * 4;
            const float4 v = *(const float4*)(Wo + (size_t)(c0 + c) * DIN + i0 + i4);
            bf16x4 pk = { (__bf16)v.x, (__bf16)v.y, (__bf16)v.z, (__bf16)v.w };
            *(bf16x4*)&sWo[c][i4] = pk;
        }
        #pragma unroll
        for (int p = 0; p < 4; ++p) {
            const int l  = p * 64 + (tid >> 2);
            const int sg = tid & 3;
            *(uint4*)&sO[l][sg * 8] = *(const uint4*)(Ob + (size_t)(l0 + l) * DIN + i0 + sg * 8);
        }
        __syncthreads();

        bf16x8 af[4], bfr[4];
        #pragma unroll
        for (int mr = 0; mr < 4; ++mr)
            af[mr] = *(const bf16x8*)&sWo[mr * 16 + n16][g * 8];
        #pragma unroll
        for (int nc = 0; nc < 4; ++nc)
            bfr[nc] = *(const bf16x8*)&sO[wv * 64 + nc * 16 + n16][g * 8];
        #pragma unroll
        for (int mr = 0; mr < 4; ++mr)
            #pragma unroll
            for (int nc = 0; nc < 4; ++nc)
                acc[mr][nc] = __builtin_amdgcn_mfma_f32_16x16x32_bf16(
                    af[mr], bfr[nc], acc[mr][nc], 0, 0, 0);
    }

    // D: row = c (mr*16 + g*4 + r), col = l (nc*16 + n16); f32 store
    #pragma unroll
    for (int mr = 0; mr < 4; ++mr) {
        const int c = c0 + mr * 16 + g * 4;
        #pragma unroll
        for (int nc = 0; nc < 4; ++nc) {
            const int l = l0 + wv * 64 + nc * 16 + n16;
            #pragma unroll
            for (int r = 0; r < 4; ++r)
                out[((size_t)b * CH + c + r) * LSEQ + l] = acc[mr][nc][r] + bo[c + r];
        }
    }
}

// ---------------------------------------------------------------------------
extern "C" void kernel_launch(void* const* d_in, const int* in_sizes, int n_in,
                              void* d_out, int out_size, void* d_ws, size_t ws_size,
                              hipStream_t stream)
{
    const float* x  = (const float*)d_in[0];
    const float* Wq = (const float*)d_in[1];
    const float* bq = (const float*)d_in[2];
    const float* Wk = (const float*)d_in[3];
    const float* bk = (const float*)d_in[4];
    const float* Wv = (const float*)d_in[5];
    const float* bv = (const float*)d_in[6];
    const float* Wo = (const float*)d_in[7];
    const float* bo = (const float*)d_in[8];
    float* out = (float*)d_out;

    // workspace: Q, K (bf16 [b][l][d]), VT (bf16 [b][d][l]), O (bf16 [b][l][d]) = 64 MB
    __bf16* Q  = (__bf16*)d_ws;
    __bf16* K  = Q  + (size_t)BS * LSEQ * DIN;
    __bf16* VT = K  + (size_t)BS * LSEQ * DIN;
    __bf16* O  = VT + (size_t)BS * DIN * LSEQ;

    qkv_proj_kernel<<<dim3(LSEQ / 64, 3, BS), 256, 0, stream>>>(
        x, Wq, bq, Wk, bk, Wv, bv, Q, K, VT);
    attn_kernel<<<dim3(BS, LSEQ / 64), 256, 0, stream>>>(Q, K, VT, O);
    out_proj_kernel<<<dim3(LSEQ / 256, CH / 64, BS), 256, 0, stream>>>(Wo, bo, O, out);
}

// Round 2
// 432.284 us; speedup vs baseline: 1.3074x; 1.3074x over previous
//
#include <hip/hip_runtime.h>
#include <stdint.h>

#define BS   8
#define CH   256    // C
#define LSEQ 4096   // H*W
#define DIN  256    // INNER
#define NT   64     // number of KV tiles
#define KT   64     // kv rows per tile

typedef __bf16 bf16x8 __attribute__((ext_vector_type(8)));
typedef __bf16 bf16x4 __attribute__((ext_vector_type(4)));
typedef float  f32x4  __attribute__((ext_vector_type(4)));

// async global->LDS, 16B per lane; LDS dest = wave-uniform base + lane*16
__device__ __forceinline__ void gload_lds16(const void* g, void* l) {
    __builtin_amdgcn_global_load_lds(
        (const __attribute__((address_space(1))) uint32_t*)g,
        (__attribute__((address_space(3))) uint32_t*)l, 16, 0, 0);
}

// ---------------------------------------------------------------------------
// Kernel 1: QKV projection. Y[l][i] = sum_c X[c][l]*W[i][c] + b[i].
// which==0 -> Q linear [l][i] bf16.
// which==1 -> K into swizzled tile image: tile(b,kt) 32KB, byte =
//             row*512 + ((2i) ^ ((row&7)<<4)), row = l&63.
// which==2 -> V into tile image second half: byte = 32768 + d*128 +
//             ((2*(l&63)) ^ ((d&7)<<4)).
// KV tile = 64KB: [K img 32KB][V img 32KB], contiguous per (b,kt).
// ---------------------------------------------------------------------------
__global__ __launch_bounds__(256) void qkv_proj_kernel(
    const float* __restrict__ x,
    const float* __restrict__ Wq, const float* __restrict__ bq,
    const float* __restrict__ Wk, const float* __restrict__ bk,
    const float* __restrict__ Wv, const float* __restrict__ bv,
    __bf16* __restrict__ Q, uint8_t* __restrict__ KV)
{
    const int b     = blockIdx.z;
    const int which = blockIdx.y;
    const int l0    = blockIdx.x * 64;

    const float* W    = (which == 0) ? Wq : (which == 1) ? Wk : Wv;
    const float* bias = (which == 0) ? bq : (which == 1) ? bk : bv;
    const float* X    = x + (size_t)b * CH * LSEQ;

    __shared__ __align__(16) __bf16 sXt[64][40];   // [l][c]
    __shared__ __align__(16) __bf16 sW[256][40];   // [i][c]

    const int tid  = threadIdx.x;
    const int wv   = tid >> 6;
    const int lane = tid & 63;
    const int g    = lane >> 4;
    const int n16  = lane & 15;

    f32x4 acc[4][4];
    #pragma unroll
    for (int i = 0; i < 4; ++i)
        #pragma unroll
        for (int j = 0; j < 4; ++j)
            acc[i][j] = f32x4{0.f, 0.f, 0.f, 0.f};

    for (int kk = 0; kk < 8; ++kk) {
        const int c0 = kk * 32;
        __syncthreads();
        #pragma unroll
        for (int p = 0; p < 8; ++p) {
            const int i  = p * 32 + (tid >> 3);
            const int c4 = (tid & 7) * 4;
            const float4 v = *(const float4*)(W + (size_t)i * CH + c0 + c4);
            bf16x4 pk = { (__bf16)v.x, (__bf16)v.y, (__bf16)v.z, (__bf16)v.w };
            *(bf16x4*)&sW[i][c4] = pk;
        }
        #pragma unroll
        for (int p = 0; p < 2; ++p) {
            const int c  = p * 16 + (tid >> 4);
            const int l4 = (tid & 15) * 4;
            const float4 v = *(const float4*)(X + (size_t)(c0 + c) * LSEQ + l0 + l4);
            sXt[l4 + 0][c] = (__bf16)v.x;
            sXt[l4 + 1][c] = (__bf16)v.y;
            sXt[l4 + 2][c] = (__bf16)v.z;
            sXt[l4 + 3][c] = (__bf16)v.w;
        }
        __syncthreads();

        bf16x8 af[4], bfr[4];
        #pragma unroll
        for (int mr = 0; mr < 4; ++mr)
            af[mr] = *(const bf16x8*)&sXt[mr * 16 + n16][g * 8];
        #pragma unroll
        for (int nc = 0; nc < 4; ++nc)
            bfr[nc] = *(const bf16x8*)&sW[wv * 64 + nc * 16 + n16][g * 8];
        #pragma unroll
        for (int mr = 0; mr < 4; ++mr)
            #pragma unroll
            for (int nc = 0; nc < 4; ++nc)
                acc[mr][nc] = __builtin_amdgcn_mfma_f32_16x16x32_bf16(
                    af[mr], bfr[nc], acc[mr][nc], 0, 0, 0);
    }

    // D fragment: row l = mr*16 + g*4 + r, col i = nc*16 + n16 (+wv*64)
    if (which == 0) {
        __bf16* out = Q + (size_t)b * LSEQ * DIN;
        #pragma unroll
        for (int nc = 0; nc < 4; ++nc) {
            const int icol = wv * 64 + nc * 16 + n16;
            const float bb = bias[icol];
            #pragma unroll
            for (int mr = 0; mr < 4; ++mr) {
                const int lrow = l0 + mr * 16 + g * 4;
                #pragma unroll
                for (int r = 0; r < 4; ++r)
                    out[(size_t)(lrow + r) * DIN + icol] = (__bf16)(acc[mr][nc][r] + bb);
            }
        }
    } else if (which == 1) {
        #pragma unroll
        for (int nc = 0; nc < 4; ++nc) {
            const int icol = wv * 64 + nc * 16 + n16;
            const float bb = bias[icol];
            #pragma unroll
            for (int mr = 0; mr < 4; ++mr) {
                #pragma unroll
                for (int r = 0; r < 4; ++r) {
                    const int lrow = l0 + mr * 16 + g * 4 + r;
                    const int kt = lrow >> 6, row = lrow & 63;
                    const size_t off = ((size_t)(b * NT + kt) << 16)
                                     + (size_t)row * 512
                                     + ((icol * 2) ^ ((row & 7) << 4));
                    *(__bf16*)(KV + off) = (__bf16)(acc[mr][nc][r] + bb);
                }
            }
        }
    } else {
        #pragma unroll
        for (int nc = 0; nc < 4; ++nc) {
            const int d  = wv * 64 + nc * 16 + n16;
            const float bb = bias[d];
            #pragma unroll
            for (int mr = 0; mr < 4; ++mr) {
                const int lrow = l0 + mr * 16 + g * 4;   // 4 consecutive l, 8B run
                const int kt = lrow >> 6, c = lrow & 63;
                bf16x4 pk;
                #pragma unroll
                for (int r = 0; r < 4; ++r)
                    pk[r] = (__bf16)(acc[mr][nc][r] + bb);
                const size_t off = ((size_t)(b * NT + kt) << 16) + 32768
                                 + (size_t)d * 128
                                 + ((2 * c) ^ ((d & 7) << 4));
                *(bf16x4*)(KV + off) = pk;
            }
        }
    }
}

// ---------------------------------------------------------------------------
// Kernel 2: flash attention v2.
// Block = 4 waves, Q-tile 128 (32 rows/wave, 2 m-frags). KV tile 64.
// KV tiles pre-swizzled in global; staged with global_load_lds (linear,
// conflict-free); double-buffered LDS; counted vmcnt(16) so next-tile loads
// stay in flight across barriers. Swizzled ds_read_b128 -> 0 bank conflicts.
// Grid (b=8, qt=32): block id % 8 == b -> each XCD's L2 holds one batch's KV.
// ---------------------------------------------------------------------------
__global__ __launch_bounds__(256) void attn_kernel(
    const __bf16* __restrict__ Q, const uint8_t* __restrict__ KV,
    __bf16* __restrict__ O)
{
    const int b   = blockIdx.x;
    const int q0  = blockIdx.y * 128;
    const int tid = threadIdx.x;
    const int wv  = tid >> 6, lane = tid & 63, g = lane >> 4, n16 = lane & 15;

    // dbuf KV tiles (64KB each: K[64][256] img + V[256][64] img), + P 16KB
    __shared__ __align__(1024) uint8_t sKV[2][65536];
    __shared__ __align__(1024) uint8_t sP[16384];     // [128 rows][128B], swizzled

    // Q fragments: 2 m-frags x 8 k-slices, rows wv*32 + m*16 + n16
    bf16x8 qf[2][8];
    #pragma unroll
    for (int m = 0; m < 2; ++m) {
        const __bf16* Qrow = Q + ((size_t)b * LSEQ + q0 + wv * 32 + m * 16 + n16) * DIN;
        #pragma unroll
        for (int ks = 0; ks < 8; ++ks)
            qf[m][ks] = *(const bf16x8*)(Qrow + ks * 32 + g * 8);
    }

    float m_i[2][4], l_i[2][4];
    #pragma unroll
    for (int m = 0; m < 2; ++m)
        #pragma unroll
        for (int r = 0; r < 4; ++r) { m_i[m][r] = -__builtin_inff(); l_i[m][r] = 0.f; }
    f32x4 accO[2][16];
    #pragma unroll
    for (int m = 0; m < 2; ++m)
        #pragma unroll
        for (int ds = 0; ds < 16; ++ds) accO[m][ds] = f32x4{0.f, 0.f, 0.f, 0.f};

    const uint8_t* KVb = KV + ((size_t)b * NT << 16);
    const float CEXP = 1.4426950408889634f / 16.0f;   // log2(e)/scale, scale=16

    // prologue: stage tile 0 into buf 0 (16 x 16B per thread = 64KB)
    #pragma unroll
    for (int p = 0; p < 16; ++p) {
        const int off = p * 4096 + tid * 16;
        gload_lds16(KVb + off, &sKV[0][off]);
    }

    for (int t = 0; t < NT; ++t) {
        const int buf = t & 1;
        if (t + 1 < NT) {
            const uint8_t* src = KVb + ((size_t)(t + 1) << 16);
            #pragma unroll
            for (int p = 0; p < 16; ++p) {
                const int off = p * 4096 + tid * 16;
                gload_lds16(src + off, &sKV[buf ^ 1][off]);
            }
            asm volatile("s_waitcnt vmcnt(16)" ::: "memory");  // cur tile done, next in flight
        } else {
            asm volatile("s_waitcnt vmcnt(0)" ::: "memory");
        }
        __builtin_amdgcn_s_barrier();
        asm volatile("" ::: "memory");

        const uint8_t* kb = sKV[buf];

        // ---- QK^T: D[qi][kj], 2 m-frags share each K fragment ----
        f32x4 sacc[2][4];
        #pragma unroll
        for (int m = 0; m < 2; ++m)
            #pragma unroll
            for (int nc = 0; nc < 4; ++nc) sacc[m][nc] = f32x4{0.f, 0.f, 0.f, 0.f};
        #pragma unroll
        for (int ks = 0; ks < 8; ++ks) {
            #pragma unroll
            for (int nc = 0; nc < 4; ++nc) {
                const int row = nc * 16 + n16;
                const bf16x8 kf = *(const bf16x8*)(kb + row * 512
                                   + ((ks * 64 + g * 16) ^ ((row & 7) << 4)));
                sacc[0][nc] = __builtin_amdgcn_mfma_f32_16x16x32_bf16(qf[0][ks], kf, sacc[0][nc], 0, 0, 0);
                sacc[1][nc] = __builtin_amdgcn_mfma_f32_16x16x32_bf16(qf[1][ks], kf, sacc[1][nc], 0, 0, 0);
            }
        }

        // ---- online softmax (per m-frag; lane rows g*4+r, cols nc*16+n16) ----
        #pragma unroll
        for (int m = 0; m < 2; ++m) {
            float scl[4];
            #pragma unroll
            for (int r = 0; r < 4; ++r) {
                float rmax = fmaxf(fmaxf(sacc[m][0][r], sacc[m][1][r]),
                                   fmaxf(sacc[m][2][r], sacc[m][3][r]));
                rmax = fmaxf(rmax, __shfl_xor(rmax, 1));
                rmax = fmaxf(rmax, __shfl_xor(rmax, 2));
                rmax = fmaxf(rmax, __shfl_xor(rmax, 4));
                rmax = fmaxf(rmax, __shfl_xor(rmax, 8));
                const float mnew = fmaxf(m_i[m][r], rmax);
                scl[r] = exp2f((m_i[m][r] - mnew) * CEXP);
                float rsum = 0.f;
                float pv[4];
                #pragma unroll
                for (int nc = 0; nc < 4; ++nc) {
                    pv[nc] = exp2f((sacc[m][nc][r] - mnew) * CEXP);
                    rsum += pv[nc];
                }
                #pragma unroll
                for (int nc = 0; nc < 4; ++nc) sacc[m][nc][r] = pv[nc];  // reuse as P
                rsum += __shfl_xor(rsum, 1);
                rsum += __shfl_xor(rsum, 2);
                rsum += __shfl_xor(rsum, 4);
                rsum += __shfl_xor(rsum, 8);
                l_i[m][r] = l_i[m][r] * scl[r] + rsum;
                m_i[m][r] = mnew;
            }
            #pragma unroll
            for (int ds = 0; ds < 16; ++ds)
                #pragma unroll
                for (int r = 0; r < 4; ++r)
                    accO[m][ds][r] *= scl[r];
            // P -> LDS (wave-private rows, swizzled; DS in-order per wave)
            #pragma unroll
            for (int r = 0; r < 4; ++r) {
                const int row = wv * 32 + m * 16 + g * 4 + r;
                #pragma unroll
                for (int nc = 0; nc < 4; ++nc) {
                    const int cb = 2 * (nc * 16 + n16);
                    *(__bf16*)(sP + row * 128 + (cb ^ ((row & 7) << 4))) =
                        (__bf16)sacc[m][nc][r];
                }
            }
        }

        // ---- PV: A = P rows (n16), B = V img rows d, 2 m share each V frag ----
        bf16x8 af[2][2];
        #pragma unroll
        for (int m = 0; m < 2; ++m)
            #pragma unroll
            for (int ks2 = 0; ks2 < 2; ++ks2) {
                const int row = wv * 32 + m * 16 + n16;
                af[m][ks2] = *(const bf16x8*)(sP + row * 128
                              + ((ks2 * 64 + g * 16) ^ ((row & 7) << 4)));
            }
        #pragma unroll
        for (int ks2 = 0; ks2 < 2; ++ks2) {
            #pragma unroll
            for (int ds = 0; ds < 16; ++ds) {
                const int d = ds * 16 + n16;
                const bf16x8 vf = *(const bf16x8*)(kb + 32768 + d * 128
                                   + ((ks2 * 64 + g * 16) ^ ((d & 7) << 4)));
                accO[0][ds] = __builtin_amdgcn_mfma_f32_16x16x32_bf16(af[0][ks2], vf, accO[0][ds], 0, 0, 0);
                accO[1][ds] = __builtin_amdgcn_mfma_f32_16x16x32_bf16(af[1][ks2], vf, accO[1][ds], 0, 0, 0);
            }
        }

        asm volatile("" ::: "memory");
        __builtin_amdgcn_s_barrier();   // all waves done reading buf before overwrite
    }

    // ---- epilogue: O[l][d] = accO / l_i ----
    #pragma unroll
    for (int m = 0; m < 2; ++m) {
        float inv[4];
        #pragma unroll
        for (int r = 0; r < 4; ++r) inv[r] = 1.f / l_i[m][r];
        __bf16* Ob = O + ((size_t)b * LSEQ + q0 + wv * 32 + m * 16) * DIN;
        #pragma unroll
        for (int ds = 0; ds < 16; ++ds)
            #pragma unroll
            for (int r = 0; r < 4; ++r)
                Ob[(size_t)(g * 4 + r) * DIN + ds * 16 + n16] =
                    (__bf16)(accO[m][ds][r] * inv[r]);
    }
}

// ---------------------------------------------------------------------------
// Kernel 3: output projection. out[b][c][l] = sum_i Wo[c][i]*O[b][l][i] + bo[c].
// ---------------------------------------------------------------------------
__global__ __launch_bounds__(256) void out_proj_kernel(
    const float* __restrict__ Wo, const float* __restrict__ bo,
    const __bf16* __restrict__ O, float* __restrict__ out)
{
    const int b   = blockIdx.z;
    const int c0  = blockIdx.y * 64;
    const int l0  = blockIdx.x * 256;
    const int tid = threadIdx.x;
    const int wv  = tid >> 6, lane = tid & 63, g = lane >> 4, n16 = lane & 15;

    __shared__ __align__(16) __bf16 sWo[64][40];   // [c][i]
    __shared__ __align__(16) __bf16 sO[256][40];   // [l][i]

    const __bf16* Ob = O + (size_t)b * LSEQ * DIN;

    f32x4 acc[4][4];
    #pragma unroll
    for (int i = 0; i < 4; ++i)
        #pragma unroll
        for (int j = 0; j < 4; ++j)
            acc[i][j] = f32x4{0.f, 0.f, 0.f, 0.f};

    for (int kk = 0; kk < 8; ++kk) {
        const int i0 = kk * 32;
        __syncthreads();
        #pragma unroll
        for (int p = 0; p < 2; ++p) {
            const int c  = p * 32 + (tid >> 3);
            const int i4 = (tid & 7) * 4;
            const float4 v = *(const float4*)(Wo + (size_t)(c0 + c) * DIN + i0 + i4);
            bf16x4 pk = { (__bf16)v.x, (__bf16)v.y, (__bf16)v.z, (__bf16)v.w };
            *(bf16x4*)&sWo[c][i4] = pk;
        }
        #pragma unroll
        for (int p = 0; p < 4; ++p) {
            const int l  = p * 64 + (tid >> 2);
            const int sg = tid & 3;
            *(uint4*)&sO[l][sg * 8] = *(const uint4*)(Ob + (size_t)(l0 + l) * DIN + i0 + sg * 8);
        }
        __syncthreads();

        bf16x8 af[4], bfr[4];
        #pragma unroll
        for (int mr = 0; mr < 4; ++mr)
            af[mr] = *(const bf16x8*)&sWo[mr * 16 + n16][g * 8];
        #pragma unroll
        for (int nc = 0; nc < 4; ++nc)
            bfr[nc] = *(const bf16x8*)&sO[wv * 64 + nc * 16 + n16][g * 8];
        #pragma unroll
        for (int mr = 0; mr < 4; ++mr)
            #pragma unroll
            for (int nc = 0; nc < 4; ++nc)
                acc[mr][nc] = __builtin_amdgcn_mfma_f32_16x16x32_bf16(
                    af[mr], bfr[nc], acc[mr][nc], 0, 0, 0);
    }

    #pragma unroll
    for (int mr = 0; mr < 4; ++mr) {
        const int c = c0 + mr * 16 + g * 4;
        #pragma unroll
        for (int nc = 0; nc < 4; ++nc) {
            const int l = l0 + wv * 64 + nc * 16 + n16;
            #pragma unroll
            for (int r = 0; r < 4; ++r)
                out[((size_t)b * CH + c + r) * LSEQ + l] = acc[mr][nc][r] + bo[c + r];
        }
    }
}

// ---------------------------------------------------------------------------
extern "C" void kernel_launch(void* const* d_in, const int* in_sizes, int n_in,
                              void* d_out, int out_size, void* d_ws, size_t ws_size,
                              hipStream_t stream)
{
    const float* x  = (const float*)d_in[0];
    const float* Wq = (const float*)d_in[1];
    const float* bq = (const float*)d_in[2];
    const float* Wk = (const float*)d_in[3];
    const float* bk = (const float*)d_in[4];
    const float* Wv = (const float*)d_in[5];
    const float* bv = (const float*)d_in[6];
    const float* Wo = (const float*)d_in[7];
    const float* bo = (const float*)d_in[8];
    float* out = (float*)d_out;

    // ws: Q bf16 16MB | KV swizzled tile images 32MB | O bf16 16MB = 64MB
    __bf16*  Q  = (__bf16*)d_ws;
    uint8_t* KV = (uint8_t*)d_ws + (16u << 20);
    __bf16*  O  = (__bf16*)((uint8_t*)d_ws + (48u << 20));

    qkv_proj_kernel<<<dim3(LSEQ / 64, 3, BS), 256, 0, stream>>>(
        x, Wq, bq, Wk, bk, Wv, bv, Q, KV);
    attn_kernel<<<dim3(BS, LSEQ / 128), 256, 0, stream>>>(Q, KV, O);
    out_proj_kernel<<<dim3(LSEQ / 256, CH / 64, BS), 256, 0, stream>>>(Wo, bo, O, out);
}